// Round 15
// baseline (68.007 us; speedup 1.0000x reference)
//
#include <hip/hip_runtime.h>
#include <stdint.h>

#define C_IN 256
#define HW   56
#define HW2  3136          // 56*56
#define SPAN 2304          // 9*256
#define TS   16
#define BKT  32

typedef __attribute__((ext_vector_type(8)))  short short8;
typedef __attribute__((ext_vector_type(4)))  float f32x4;
typedef __attribute__((ext_vector_type(16))) float f32x16;
typedef float f32x4u __attribute__((ext_vector_type(4), aligned(4)));   // 4B-aligned vector load

// d_ws layout: [0..127]: rows (32 x int32). [512 ...]: Wpack ushort[73728]

// ---------------------------------------------------------------------------
// Kernel 1: hash -> 32 gathered row ids (byte-identical to all PASS rounds).
// ---------------------------------------------------------------------------
__global__ void hash_rows_kernel(const float* __restrict__ x,
                                 const float* __restrict__ a,
                                 const int*   __restrict__ table,
                                 int*         __restrict__ rows_out) {
    __shared__ float rd[256];
    __shared__ float rn[256];
    const int t = threadIdx.x;
    float dv = 0.f, nq = 0.f;
    for (int k = t; k < SPAN; k += 256) {
        const int p = k >> 8;
        const int c = k & 255;
        const int i = p / 3, j = p % 3;
        float v = 0.f;
        if (i >= 1 && j >= 1) v = x[c * HW2 + (i - 1) * HW + (j - 1)];
        dv += a[k] * v;
        nq += v * v;
    }
    rd[t] = dv; rn[t] = nq;
    __syncthreads();
    for (int s = 128; s > 0; s >>= 1) {
        if (t < s) { rd[t] += rd[t + s]; rn[t] += rn[t + s]; }
        __syncthreads();
    }
    if (t == 0) {
        const float nrm = sqrtf(rn[0]);
        const float sv  = rd[0] / nrm
                        + 0.5f * (a[SPAN] + a[SPAN+1] + a[SPAN+2] + a[SPAN+3] + a[SPAN+4]);
        const int idx = ((int)fabsf(floorf(sv))) % TS;
        #pragma unroll
        for (int b = 0; b < BKT; ++b) rows_out[b] = table[idx * BKT + b];
    }
}

// ---------------------------------------------------------------------------
// Kernel 2: build Wpack for 32x32x16 A-fragments (byte-identical to rounds
// 12-14 PASS). Chunk Q = ccb*18 + p*2 + ch16 (144 chunks of K=16).
// Lane l elem j: A[brow = l&31][k = p*256 + ccb*32 + ch16*16 + (l>>5)*8 + j].
// ---------------------------------------------------------------------------
__global__ void build_wpack_kernel(const float* __restrict__ kernels,
                                   const int*   __restrict__ rows,
                                   unsigned short* __restrict__ wp) {
    const int idx   = blockIdx.x * 256 + threadIdx.x;   // 0..73727
    const int j     = idx & 7;
    const int l     = (idx >> 3) & 63;
    const int Q     = idx >> 9;          // 0..143
    const int ccb   = Q / 18;
    const int rem   = Q % 18;
    const int p     = rem >> 1;
    const int ch16  = rem & 1;
    const int brow  = l & 31;
    const int khalf = l >> 5;
    const int k     = p * 256 + ccb * 32 + ch16 * 16 + khalf * 8 + j;
    const int row   = rows[brow];
    const float v = kernels[(size_t)row * SPAN + k] * 16.0f;
    unsigned u = __builtin_bit_cast(unsigned, v);
    u = (u + 0x7fffu + ((u >> 16) & 1u)) >> 16;       // RNE fp32->bf16
    wp[idx] = (unsigned short)u;
}

// ---------------------------------------------------------------------------
// Kernel 3: implicit-GEMM via mfma_f32_32x32x16_bf16 — round-14 PASS chassis
// (8-wave block, in-block K-reduce, clean stores), with DEEPER LOAD BATCHING:
//   per dd (halo row), issue ALL 22 independent loads up front —
//   16 V-windows (both ch16 halves) + 6 A-chunks — before any MFMA consumes
//   them. r14 issued 8 V at a time -> one L2 latency exposed per batch of 8;
//   this halves the number of exposed latency events per wave.
//   VGPR: V 64 + A 24 + acc 16 + misc ~20 = ~124 < 128 (4 waves/SIMD kept).
// Values, accumulation order, epilogue byte-identical to r14.
// ---------------------------------------------------------------------------
__global__ __launch_bounds__(512, 4)
void alsh_mfma_kernel(const float* __restrict__ x,
                      const unsigned short* __restrict__ wp,
                      float* __restrict__ out) {
    __shared__ float red[8 * 1024];             // 32KB: 8 waves x (32 b0 x 32 col)

    const int b  = blockIdx.x;                  // 0..1567
    const int ct = (b & 7) * 196 + (b >> 3);    // XCD chunk swizzle (1568 = 8*196)

    const int t     = threadIdx.x;              // 0..511
    const int lane  = t & 63;
    const int wid   = t >> 6;                   // 0..7
    const int ccb   = wid;                      // K-slice = one 32-ch block
    const int col   = lane & 31;                // B-col / D-col
    const int khalf = lane >> 5;                // k-half 0..1
    const int s0    = ct * 32;                  // block's base column
    const int n     = s0 / HW2;                 // block-uniform (3136 = 98*32)
    const int s0img = s0 - n * HW2;
    const int sl    = s0img + col;              // lane's spatial idx in image
    const int h     = sl / HW;
    const int w     = sl - h * HW;
    const float* xn = x + (size_t)n * (C_IN * HW2);
    const short8* wpv = (const short8*)wp;

    f32x16 acc = {0.f,0.f,0.f,0.f, 0.f,0.f,0.f,0.f, 0.f,0.f,0.f,0.f, 0.f,0.f,0.f,0.f};

    const int cc = ccb * 32;
    #pragma unroll
    for (int dd = 0; dd < 3; ++dd) {            // di = dd-1
        const int di     = dd - 1;
        const int rowpos = sl + di * HW;        // pos at dj=0
        const int posm   = rowpos - 1;          // window base (dj=-1)
        const int pc     = posm < 0 ? 0 : (posm > HW2 - 4 ? HW2 - 4 : posm);
        const bool shifted = (pc != posm);      // edge lanes only
        const int ih = h + di;

        // ---- issue all 22 independent loads for this dd ----
        f32x4 V[16];                            // v = ch16*8 + j
        #pragma unroll
        for (int v = 0; v < 16; ++v) {
            const int ch = cc + (v >> 3) * 16 + khalf * 8 + (v & 7);
            V[v] = *(const f32x4u*)(xn + (size_t)ch * HW2 + pc);
        }
        short8 A6[6];                           // c2 = dd2*2 + ch16
        #pragma unroll
        for (int c2 = 0; c2 < 6; ++c2)
            A6[c2] = wpv[(ccb * 18 + dd * 6 + c2) * 64 + lane];

        // ---- consume: ch16-major, dj-inner (r14 accumulation order) ----
        #pragma unroll
        for (int ch16 = 0; ch16 < 2; ++ch16) {
            #pragma unroll
            for (int dd2 = 0; dd2 < 3; ++dd2) { // dj = dd2-1
                const int dj = dd2 - 1;
                const int iw = w + dj;
                const bool ok = ((unsigned)ih < (unsigned)HW) & ((unsigned)iw < (unsigned)HW);
                const int voff = rowpos + dj;

                short8 bf;
                #pragma unroll
                for (int j = 0; j < 8; ++j) {
                    float v = V[ch16 * 8 + j][dd2];   // = x[ch][voff] when !shifted
                    if (shifted) {              // exec-masked scalar fallback
                        const int vc = voff < 0 ? 0 : (voff > HW2 - 1 ? HW2 - 1 : voff);
                        v = xn[(size_t)(cc + ch16 * 16 + khalf * 8 + j) * HW2 + vc];
                    }
                    v = ok ? v : 0.f;
                    const unsigned u = __builtin_bit_cast(unsigned, v);
                    bf[j] = (short)((u + 0x8000u) >> 16);   // fp32->bf16 round
                }

                acc = __builtin_amdgcn_mfma_f32_32x32x16_bf16(A6[dd2 * 2 + ch16], bf, acc, 0, 0, 0);
            }
        }
    }

    // ---- in-block K-reduce (r14-proven float/float LDS idiom) ----
    // C/D: col = lane&31, row b0 = (reg&3) + 8*(reg>>2) + 4*khalf
    const int base = wid * 1024;
    #pragma unroll
    for (int i2 = 0; i2 < 16; ++i2) {
        const int b0 = (i2 & 3) + 8 * (i2 >> 2) + 4 * khalf;
        red[base + b0 * 32 + col] = acc[i2];
    }
    __syncthreads();

    float* on = out + (size_t)n * (BKT * HW2) + s0img;
    #pragma unroll
    for (int e = 0; e < 2; ++e) {
        const int elem = e * 512 + t;           // 0..1023 = b0*32 + c
        float s = red[elem];
        #pragma unroll
        for (int w2 = 1; w2 < 8; ++w2) s += red[w2 * 1024 + elem];
        const int b0 = elem >> 5;
        const int c  = elem & 31;
        on[(size_t)b0 * HW2 + c] = s;
    }
}

// ---------------------------------------------------------------------------
extern "C" void kernel_launch(void* const* d_in, const int* in_sizes, int n_in,
                              void* d_out, int out_size, void* d_ws, size_t ws_size,
                              hipStream_t stream) {
    const float* x       = (const float*)d_in[0];
    const float* kernels = (const float*)d_in[1];
    const float* a       = (const float*)d_in[2];
    const int*   table   = (const int*)d_in[3];
    float* out = (float*)d_out;
    int*   rows = (int*)d_ws;
    unsigned short* wpack = (unsigned short*)((char*)d_ws + 512);

    hipLaunchKernelGGL(hash_rows_kernel, dim3(1), dim3(256), 0, stream,
                       x, a, table, rows);
    hipLaunchKernelGGL(build_wpack_kernel, dim3(288), dim3(256), 0, stream,
                       kernels, rows, wpack);
    hipLaunchKernelGGL(alsh_mfma_kernel, dim3(1568), dim3(512), 0, stream,
                       x, wpack, out);
}

// Round 16
// 49.774 us; speedup vs baseline: 1.3663x; 1.3663x over previous
//
#include <hip/hip_runtime.h>
#include <stdint.h>

#define C_IN 256
#define HW   56
#define HW2  3136          // 56*56
#define SPAN 2304          // 9*256
#define TS   16
#define BKT  32

typedef __attribute__((ext_vector_type(8)))  short short8;
typedef __attribute__((ext_vector_type(4)))  float f32x4;
typedef __attribute__((ext_vector_type(16))) float f32x16;
typedef float f32x4u __attribute__((ext_vector_type(4), aligned(4)));   // 4B-aligned vector load

// d_ws layout: [0..127]: rows (32 x int32). [512 ...]: Wpack ushort[73728]

// ---------------------------------------------------------------------------
// Kernel 1: hash -> 32 gathered row ids (byte-identical to all PASS rounds).
// ---------------------------------------------------------------------------
__global__ void hash_rows_kernel(const float* __restrict__ x,
                                 const float* __restrict__ a,
                                 const int*   __restrict__ table,
                                 int*         __restrict__ rows_out) {
    __shared__ float rd[256];
    __shared__ float rn[256];
    const int t = threadIdx.x;
    float dv = 0.f, nq = 0.f;
    for (int k = t; k < SPAN; k += 256) {
        const int p = k >> 8;
        const int c = k & 255;
        const int i = p / 3, j = p % 3;
        float v = 0.f;
        if (i >= 1 && j >= 1) v = x[c * HW2 + (i - 1) * HW + (j - 1)];
        dv += a[k] * v;
        nq += v * v;
    }
    rd[t] = dv; rn[t] = nq;
    __syncthreads();
    for (int s = 128; s > 0; s >>= 1) {
        if (t < s) { rd[t] += rd[t + s]; rn[t] += rn[t + s]; }
        __syncthreads();
    }
    if (t == 0) {
        const float nrm = sqrtf(rn[0]);
        const float sv  = rd[0] / nrm
                        + 0.5f * (a[SPAN] + a[SPAN+1] + a[SPAN+2] + a[SPAN+3] + a[SPAN+4]);
        const int idx = ((int)fabsf(floorf(sv))) % TS;
        #pragma unroll
        for (int b = 0; b < BKT; ++b) rows_out[b] = table[idx * BKT + b];
    }
}

// ---------------------------------------------------------------------------
// Kernel 2: build Wpack for 32x32x16 A-fragments (byte-identical to rounds
// 12-14 PASS). Chunk Q = ccb*18 + p*2 + ch16 (144 chunks of K=16).
// Lane l elem j: A[brow = l&31][k = p*256 + ccb*32 + ch16*16 + (l>>5)*8 + j].
// ---------------------------------------------------------------------------
__global__ void build_wpack_kernel(const float* __restrict__ kernels,
                                   const int*   __restrict__ rows,
                                   unsigned short* __restrict__ wp) {
    const int idx   = blockIdx.x * 256 + threadIdx.x;   // 0..73727
    const int j     = idx & 7;
    const int l     = (idx >> 3) & 63;
    const int Q     = idx >> 9;          // 0..143
    const int ccb   = Q / 18;
    const int rem   = Q % 18;
    const int p     = rem >> 1;
    const int ch16  = rem & 1;
    const int brow  = l & 31;
    const int khalf = l >> 5;
    const int k     = p * 256 + ccb * 32 + ch16 * 16 + khalf * 8 + j;
    const int row   = rows[brow];
    const float v = kernels[(size_t)row * SPAN + k] * 16.0f;
    unsigned u = __builtin_bit_cast(unsigned, v);
    u = (u + 0x7fffu + ((u >> 16) & 1u)) >> 16;       // RNE fp32->bf16
    wp[idx] = (unsigned short)u;
}

// ---------------------------------------------------------------------------
// Kernel 3: implicit-GEMM via mfma_f32_32x32x16_bf16 — round-14 PASS body
// verbatim (V[8] batching; r15's deeper batching spilled at the 64-VGPR
// allocator ceiling), with the in-block K-reduce LDS HALVED to 16KB:
//   two-phase reduce — waves 0-3 WRITE acc to region (wid&3), barrier,
//   waves 4-7 ADD into the same region, barrier, then 512 threads sum the
//   4 regions and store. Tests the LDS-residency-cap theory (r14: 32KB
//   block showed only ~34% occupancy despite VGPR 52).
// ---------------------------------------------------------------------------
__global__ __launch_bounds__(512, 4)
void alsh_mfma_kernel(const float* __restrict__ x,
                      const unsigned short* __restrict__ wp,
                      float* __restrict__ out) {
    __shared__ float red[4 * 1024];             // 16KB: 4 regions x (32 b0 x 32 col)

    const int b  = blockIdx.x;                  // 0..1567
    const int ct = (b & 7) * 196 + (b >> 3);    // XCD chunk swizzle (1568 = 8*196)

    const int t     = threadIdx.x;              // 0..511
    const int lane  = t & 63;
    const int wid   = t >> 6;                   // 0..7
    const int ccb   = wid;                      // K-slice = one 32-ch block
    const int col   = lane & 31;                // B-col / D-col
    const int khalf = lane >> 5;                // k-half 0..1
    const int s0    = ct * 32;                  // block's base column
    const int n     = s0 / HW2;                 // block-uniform (3136 = 98*32)
    const int s0img = s0 - n * HW2;
    const int sl    = s0img + col;              // lane's spatial idx in image
    const int h     = sl / HW;
    const int w     = sl - h * HW;
    const float* xn = x + (size_t)n * (C_IN * HW2);
    const short8* wpv = (const short8*)wp;

    f32x16 acc = {0.f,0.f,0.f,0.f, 0.f,0.f,0.f,0.f, 0.f,0.f,0.f,0.f, 0.f,0.f,0.f,0.f};

    const int cc = ccb * 32;
    #pragma unroll
    for (int dd = 0; dd < 3; ++dd) {            // di = dd-1
        const int di     = dd - 1;
        const int rowpos = sl + di * HW;        // pos at dj=0
        const int posm   = rowpos - 1;          // window base (dj=-1)
        const int pc     = posm < 0 ? 0 : (posm > HW2 - 4 ? HW2 - 4 : posm);
        const bool shifted = (pc != posm);      // edge lanes only
        const int ih = h + di;

        #pragma unroll
        for (int ch16 = 0; ch16 < 2; ++ch16) {
            f32x4 V[8];
            #pragma unroll
            for (int j = 0; j < 8; ++j) {
                const int ch = cc + ch16 * 16 + khalf * 8 + j;
                V[j] = *(const f32x4u*)(xn + (size_t)ch * HW2 + pc);
            }

            #pragma unroll
            for (int dd2 = 0; dd2 < 3; ++dd2) { // dj = dd2-1
                const int dj = dd2 - 1;
                const int iw = w + dj;
                const bool ok = ((unsigned)ih < (unsigned)HW) & ((unsigned)iw < (unsigned)HW);
                const int voff = rowpos + dj;

                short8 bf;
                #pragma unroll
                for (int j = 0; j < 8; ++j) {
                    float v = V[j][dd2];        // = x[ch][voff] when !shifted
                    if (shifted) {              // exec-masked scalar fallback
                        const int vc = voff < 0 ? 0 : (voff > HW2 - 1 ? HW2 - 1 : voff);
                        v = xn[(size_t)(cc + ch16 * 16 + khalf * 8 + j) * HW2 + vc];
                    }
                    v = ok ? v : 0.f;
                    const unsigned u = __builtin_bit_cast(unsigned, v);
                    bf[j] = (short)((u + 0x8000u) >> 16);   // fp32->bf16 round
                }

                const int Q = ccb * 18 + (dd * 3 + dd2) * 2 + ch16;
                const short8 a = wpv[Q * 64 + lane];
                acc = __builtin_amdgcn_mfma_f32_32x32x16_bf16(a, bf, acc, 0, 0, 0);
            }
        }
    }

    // ---- in-block K-reduce, two-phase, 16KB LDS ----
    // C/D: col = lane&31, row b0 = (reg&3) + 8*(reg>>2) + 4*khalf (r12-proven)
    const int base = (wid & 3) * 1024;
    if (wid < 4) {
        #pragma unroll
        for (int i2 = 0; i2 < 16; ++i2) {
            const int b0 = (i2 & 3) + 8 * (i2 >> 2) + 4 * khalf;
            red[base + b0 * 32 + col] = acc[i2];
        }
    }
    __syncthreads();
    if (wid >= 4) {
        #pragma unroll
        for (int i2 = 0; i2 < 16; ++i2) {
            const int b0 = (i2 & 3) + 8 * (i2 >> 2) + 4 * khalf;
            red[base + b0 * 32 + col] += acc[i2];
        }
    }
    __syncthreads();

    float* on = out + (size_t)n * (BKT * HW2) + s0img;
    #pragma unroll
    for (int e = 0; e < 2; ++e) {
        const int elem = e * 512 + t;           // 0..1023 = b0*32 + c
        const float s = red[elem] + red[1024 + elem] + red[2048 + elem] + red[3072 + elem];
        const int b0 = elem >> 5;
        const int c  = elem & 31;
        on[(size_t)b0 * HW2 + c] = s;
    }
}

// ---------------------------------------------------------------------------
extern "C" void kernel_launch(void* const* d_in, const int* in_sizes, int n_in,
                              void* d_out, int out_size, void* d_ws, size_t ws_size,
                              hipStream_t stream) {
    const float* x       = (const float*)d_in[0];
    const float* kernels = (const float*)d_in[1];
    const float* a       = (const float*)d_in[2];
    const int*   table   = (const int*)d_in[3];
    float* out = (float*)d_out;
    int*   rows = (int*)d_ws;
    unsigned short* wpack = (unsigned short*)((char*)d_ws + 512);

    hipLaunchKernelGGL(hash_rows_kernel, dim3(1), dim3(256), 0, stream,
                       x, a, table, rows);
    hipLaunchKernelGGL(build_wpack_kernel, dim3(288), dim3(256), 0, stream,
                       kernels, rows, wpack);
    hipLaunchKernelGGL(alsh_mfma_kernel, dim3(1568), dim3(512), 0, stream,
                       x, wpack, out);
}